// Round 6
// baseline (298.383 us; speedup 1.0000x reference)
//
#include <hip/hip_runtime.h>
#include <hip/hip_bf16.h>

#define LEAK  0.2f
#define NPB   200       // nodes per dst-bucket -> K = ceil(N/NPB) = 500
#define CAP   8192      // padded per-bucket capacity (mean 6400+200, sigma 80)
#define CAPSH 13        // log2(CAP)
#define SBITS 17        // bits for src id (N=100000 < 2^17)
#define SMASK 0x1FFFF
#define CHUNK 4096      // edges per kbin block (8 per thread at 512 thr)

// pack two fp32 -> bf16x2 (RNE)
__device__ __forceinline__ unsigned pkbf(float a, float b) {
    unsigned ua = __float_as_uint(a), ub = __float_as_uint(b);
    ua += 0x7fff + ((ua >> 16) & 1);
    ub += 0x7fff + ((ub >> 16) & 1);
    return (ua >> 16) | (ub & 0xffff0000u);
}

// ---------------------------------------------------------------------------
// kbin: probe edge_index layout (int64 vs int32), LDS histogram of
// dst-buckets, in-place scan, reserve per-bucket runs (1 global atomic per
// block,bucket), stage int2 in LDS, write packed (s | dloc<<17) records into
// padded per-bucket slices of `binned`.
// ---------------------------------------------------------------------------
__global__ __launch_bounds__(512) void kbin(const int* __restrict__ ei, int E, int K,
                                            int* __restrict__ cursor,
                                            int* __restrict__ binned) {
    __shared__ int hist[512], lo[512], gb[512], lc[512];
    __shared__ int2 stag[CHUNK];
    __shared__ int probe;
    int t = threadIdx.x;
    hist[t] = 0;
    if (t == 0) probe = 0;
    __syncthreads();
    if (t < 256) {
        int zc = 0;
#pragma unroll
        for (int j = 0; j < 4; j++) zc += (ei[(t * 4 + j) * 2 + 1] == 0) ? 1 : 0;
        if (zc) atomicAdd(&probe, zc);
    }
    __syncthreads();
    int f = (probe == 1024);
    int e0 = blockIdx.x * CHUNK;
    int ss[8], dd[8];
#pragma unroll
    for (int i = 0; i < 8; i++) {
        int e = e0 + t + 512 * i;
        ss[i] = -1;
        dd[i] = 0;
        if (e < E) {
            int s, d;
            if (f) { s = ei[2 * (long long)e]; d = ei[2 * ((long long)e + E)]; }
            else   { s = ei[e];                d = ei[(long long)e + E]; }
            ss[i] = s;
            dd[i] = d;
            atomicAdd(&hist[d / NPB], 1);
        }
    }
    __syncthreads();
    int v = hist[t], x = v;
    for (int o = 1; o < 512; o <<= 1) {
        int y = (t >= o) ? hist[t - o] : 0;
        __syncthreads();
        x += y;
        hist[t] = x;
        __syncthreads();
    }
    int tb = x - v;
    lo[t] = tb;
    lc[t] = tb;
    if (t < K && v) {
        int rel = atomicAdd(&cursor[t], v);
        gb[t] = (t << CAPSH) + rel;
    }
    __syncthreads();
#pragma unroll
    for (int i = 0; i < 8; i++) {
        if (ss[i] >= 0) {
            int bk = dd[i] / NPB;
            int pos = atomicAdd(&lc[bk], 1);
            stag[pos] = make_int2(ss[i], dd[i]);
        }
    }
    __syncthreads();
    int cnt = min(CHUNK, E - e0);
#pragma unroll
    for (int i = 0; i < 8; i++) {
        int idx = t + 512 * i;
        if (idx < cnt) {
            int2 sd2 = stag[idx];
            int bk = sd2.y / NPB;
            int dloc = sd2.y - bk * NPB;
            int gpos = gb[bk] + (idx - lo[bk]);
            if (gpos < ((bk + 1) << CAPSH))           // OOB safety clamp
                binned[gpos] = sd2.x | (dloc << SBITS);
        }
    }
}

// ---------------------------------------------------------------------------
// k1: h1[N,32](bf16) = x[N,128] @ W1[128,32]; a1s/a1d[N,2] attention scalars.
// ---------------------------------------------------------------------------
__global__ __launch_bounds__(256) void k1(const float* __restrict__ x,
                                          const float* __restrict__ W1,
                                          const float* __restrict__ atts,
                                          const float* __restrict__ attd,
                                          uint2* __restrict__ h1b,
                                          float* __restrict__ a1s,
                                          float* __restrict__ a1d, int N) {
    __shared__ float Ws[128 * 32];
    __shared__ float xs[64 * 132];
    int t = threadIdx.x;
    const float4* W4 = (const float4*)W1;
    float4* Ws4 = (float4*)Ws;
#pragma unroll
    for (int i = 0; i < 4; i++) Ws4[t + 256 * i] = W4[t + 256 * i];
    long long node0 = (long long)blockIdx.x * 64;
    const float4* x4 = (const float4*)x;
    float4* xs4 = (float4*)xs;
#pragma unroll
    for (int i = 0; i < 8; i++) {
        int idx = t + 256 * i;
        int row = idx >> 5, col = idx & 31;
        long long n = node0 + row;
        float4 v = make_float4(0.f, 0.f, 0.f, 0.f);
        if (n < N) v = x4[n * 32 + col];
        xs4[row * 33 + col] = v;
    }
    __syncthreads();

    int cg = t & 7, ns = t >> 3;
    const float4* xr0 = (const float4*)(xs + (ns * 2) * 132);
    const float4* xr1 = (const float4*)(xs + (ns * 2 + 1) * 132);
    float acc0[4] = {0.f, 0.f, 0.f, 0.f}, acc1[4] = {0.f, 0.f, 0.f, 0.f};
#pragma unroll 8
    for (int k4 = 0; k4 < 32; k4++) {
        float4 xa = xr0[k4], xb = xr1[k4];
        float av[4] = {xa.x, xa.y, xa.z, xa.w};
        float bv[4] = {xb.x, xb.y, xb.z, xb.w};
#pragma unroll
        for (int i = 0; i < 4; i++) {
            float4 w = Ws4[(k4 * 4 + i) * 8 + cg];
            acc0[0] = fmaf(av[i], w.x, acc0[0]);
            acc0[1] = fmaf(av[i], w.y, acc0[1]);
            acc0[2] = fmaf(av[i], w.z, acc0[2]);
            acc0[3] = fmaf(av[i], w.w, acc0[3]);
            acc1[0] = fmaf(bv[i], w.x, acc1[0]);
            acc1[1] = fmaf(bv[i], w.y, acc1[1]);
            acc1[2] = fmaf(bv[i], w.z, acc1[2]);
            acc1[3] = fmaf(bv[i], w.w, acc1[3]);
        }
    }
    long long gn0 = node0 + ns * 2, gn1 = gn0 + 1;
    if (gn0 < N) h1b[gn0 * 8 + cg] = make_uint2(pkbf(acc0[0], acc0[1]),
                                                pkbf(acc0[2], acc0[3]));
    if (gn1 < N) h1b[gn1 * 8 + cg] = make_uint2(pkbf(acc1[0], acc1[1]),
                                                pkbf(acc1[2], acc1[3]));

    float ps0 = 0.f, pd0 = 0.f, ps1 = 0.f, pd1 = 0.f;
#pragma unroll
    for (int i = 0; i < 4; i++) {
        float aa = atts[cg * 4 + i], dd = attd[cg * 4 + i];
        ps0 = fmaf(acc0[i], aa, ps0);
        pd0 = fmaf(acc0[i], dd, pd0);
        ps1 = fmaf(acc1[i], aa, ps1);
        pd1 = fmaf(acc1[i], dd, pd1);
    }
#pragma unroll
    for (int m = 1; m < 4; m <<= 1) {
        ps0 += __shfl_xor(ps0, m, 64);
        pd0 += __shfl_xor(pd0, m, 64);
        ps1 += __shfl_xor(ps1, m, 64);
        pd1 += __shfl_xor(pd1, m, 64);
    }
    if ((cg & 3) == 0) {
        int hd = cg >> 2;
        if (gn0 < N) { a1s[gn0 * 2 + hd] = ps0; a1d[gn0 * 2 + hd] = pd0; }
        if (gn1 < N) { a1s[gn1 * 2 + hd] = ps1; a1d[gn1 * 2 + hd] = pd1; }
    }
}

// ---------------------------------------------------------------------------
// kfused: one block per bucket.
// Phase 1: bucket CSR in LDS (self-loop inserted at slot 0 of each node),
//          per-edge attention weights computed ONCE (both heads, bf16x2 in
//          lwu), per-(node,head) weight sums via LDS float atomics (lws),
//          srcs(+self)/off/deg streamed to global for kagg2.
// Phase 2: 8 waves aggregate 200 nodes: per lane-edge just LDS s + LDS w +
//          8B bf16x4 h1 load + 4 fma. Fused epilogue: normalize + bias +
//          ELU + W2 proj + layer-2 attn scalars -> pk.
// ---------------------------------------------------------------------------
__global__ __launch_bounds__(512) void kfused(const int* __restrict__ cursor,
                                              const int* __restrict__ binned,
                                              const uint2* __restrict__ h1b,
                                              const float* __restrict__ a1s,
                                              const float* __restrict__ a1d,
                                              const float* __restrict__ b1,
                                              const float* __restrict__ W2,
                                              const float* __restrict__ as2,
                                              const float* __restrict__ ad2,
                                              float4* __restrict__ pk,
                                              int* __restrict__ srcs,
                                              int* __restrict__ off,
                                              int* __restrict__ deg, int N) {
    __shared__ int lsrc[CAP];                 // 32 KB
    __shared__ unsigned lwu[CAP];             // 32 KB (bf16x2 per edge)
    __shared__ int ldeg[NPB], lcur[NPB], loff[NPB];
    __shared__ float lws[NPB * 2];
    __shared__ float2 la1d[NPB];
    __shared__ int sd[512];
    __shared__ int stot;
    int b = blockIdx.x, t = threadIdx.x;
    int node0 = b * NPB;
    int nn = min(NPB, N - node0);
    int cnt = cursor[b];
    if (cnt > CAP - NPB) cnt = CAP - NPB;     // OOB safety (statistically never)
    const int* bb = binned + ((long long)b << CAPSH);
    if (t < NPB) {
        ldeg[t] = 0;
        if (t < nn) la1d[t] = ((const float2*)a1d)[node0 + t];
    }
    __syncthreads();
    for (int i = t; i < cnt; i += 512) atomicAdd(&ldeg[bb[i] >> SBITS], 1);
    __syncthreads();
    int v = (t < nn) ? ldeg[t] : 0;
    int seg = (t < nn) ? v + 1 : 0;           // +1: self-loop slot
    int x = seg;
    sd[t] = x;
    __syncthreads();
    for (int o = 1; o < 512; o <<= 1) {
        int y = (t >= o) ? sd[t - o] : 0;
        __syncthreads();
        x += y;
        sd[t] = x;
        __syncthreads();
    }
    if (t < nn) {
        int rel = x - seg;
        loff[t] = rel;
        lcur[t] = rel + 1;                    // slot 0 = self-loop
        off[node0 + t] = (b << CAPSH) + rel;
        deg[node0 + t] = seg;
        // self-loop weight + init lws
        int n = node0 + t;
        float2 as = ((const float2*)a1s)[n];
        float2 ad = la1d[t];
        float al0 = as.x + ad.x, al1 = as.y + ad.y;
        al0 = al0 > 0.f ? al0 : LEAK * al0;
        al1 = al1 > 0.f ? al1 : LEAK * al1;
        float w0 = __expf(al0), w1 = __expf(al1);
        lws[2 * t] = w0;
        lws[2 * t + 1] = w1;
        lsrc[rel] = n;
        lwu[rel] = pkbf(w0, w1);
    }
    if (t == nn - 1) stot = x;                // total entries incl selfs
    __syncthreads();
    // scatter edges + per-edge weights (computed once)
    for (int i = t; i < cnt; i += 512) {
        int p = bb[i];
        int s = p & SMASK, dloc = p >> SBITS;
        float2 as = ((const float2*)a1s)[s];
        float2 ad = la1d[dloc];
        float al0 = as.x + ad.x, al1 = as.y + ad.y;
        al0 = al0 > 0.f ? al0 : LEAK * al0;
        al1 = al1 > 0.f ? al1 : LEAK * al1;
        float w0 = __expf(al0), w1 = __expf(al1);
        atomicAdd(&lws[2 * dloc], w0);
        atomicAdd(&lws[2 * dloc + 1], w1);
        int pos = atomicAdd(&lcur[dloc], 1);
        lsrc[pos] = s;
        lwu[pos] = pkbf(w0, w1);
    }
    __syncthreads();
    int tot = stot;
    for (int i = t; i < tot; i += 512) srcs[((long long)b << CAPSH) + i] = lsrc[i];

    // ---- phase 2 ----
    int wv = t >> 6, lane = t & 63;
    int e8 = lane >> 3, c4 = lane & 7, hd = c4 >> 2;
    for (int ni = wv; ni < nn; ni += 8) {
        int base = loff[ni], g = ldeg[ni] + 1;
        float4 acc = make_float4(0.f, 0.f, 0.f, 0.f);
        for (int tt = e8; tt < g; tt += 8) {
            int s = lsrc[base + tt];
            unsigned wp = lwu[base + tt];
            float w = __uint_as_float(hd ? (wp & 0xffff0000u) : (wp << 16));
            uint2 hb = h1b[(size_t)s * 8 + c4];
            float h0 = __uint_as_float(hb.x << 16);
            float h1v = __uint_as_float(hb.x & 0xffff0000u);
            float h2 = __uint_as_float(hb.y << 16);
            float h3 = __uint_as_float(hb.y & 0xffff0000u);
            acc.x = fmaf(w, h0, acc.x);
            acc.y = fmaf(w, h1v, acc.y);
            acc.z = fmaf(w, h2, acc.z);
            acc.w = fmaf(w, h3, acc.w);
        }
#pragma unroll
        for (int m = 8; m < 64; m <<= 1) {
            acc.x += __shfl_xor(acc.x, m, 64);
            acc.y += __shfl_xor(acc.y, m, 64);
            acc.z += __shfl_xor(acc.z, m, 64);
            acc.w += __shfl_xor(acc.w, m, 64);
        }
        float inv = 1.f / (lws[2 * ni + hd] + 1e-16f);
        float4 bv = ((const float4*)b1)[c4];
        float4 t1;
        t1.x = acc.x * inv + bv.x;
        t1.y = acc.y * inv + bv.y;
        t1.z = acc.z * inv + bv.z;
        t1.w = acc.w * inv + bv.w;
        t1.x = t1.x > 0.f ? t1.x : __expf(t1.x) - 1.f;
        t1.y = t1.y > 0.f ? t1.y : __expf(t1.y) - 1.f;
        t1.z = t1.z > 0.f ? t1.z : __expf(t1.z) - 1.f;
        t1.w = t1.w > 0.f ? t1.w : __expf(t1.w) - 1.f;
        const float4* W24 = (const float4*)W2;
        float4 wA = W24[c4 * 2], wB = W24[c4 * 2 + 1];
        float p0 = t1.x * wA.x + t1.y * wA.z + t1.z * wB.x + t1.w * wB.z;
        float p1 = t1.x * wA.y + t1.y * wA.w + t1.z * wB.y + t1.w * wB.w;
#pragma unroll
        for (int m = 1; m < 8; m <<= 1) {
            p0 += __shfl_xor(p0, m, 64);
            p1 += __shfl_xor(p1, m, 64);
        }
        if (lane == 0)
            pk[node0 + ni] = make_float4(p0 * as2[0] + p1 * as2[1], p0, p1,
                                         p0 * ad2[0] + p1 * ad2[1]);
    }
}

// ---------------------------------------------------------------------------
// kagg2: layer-2 gather, one wave per node (self-loop already in srcs),
// 1 packed 16B load per edge, + log_softmax -> out
// ---------------------------------------------------------------------------
__global__ __launch_bounds__(256) void kagg2(const int* __restrict__ off,
                                             const int* __restrict__ deg,
                                             const int* __restrict__ srcs,
                                             const float4* __restrict__ pk,
                                             const float* __restrict__ b2,
                                             float* __restrict__ out, int N) {
    int wv = threadIdx.x >> 6;
    int lane = threadIdx.x & 63;
    int n = blockIdx.x * 4 + wv;
    if (n >= N) return;
    float adn = pk[n].w;
    int base = off[n], g = deg[n];
    float a0 = 0.f, a1v = 0.f, ws = 0.f;
    for (int t = lane; t < g; t += 64) {
        int s = srcs[base + t];
        float4 p = pk[s];
        float al = p.x + adn;
        al = al > 0.f ? al : LEAK * al;
        float w = __expf(al);
        a0 = fmaf(w, p.y, a0);
        a1v = fmaf(w, p.z, a1v);
        ws += w;
    }
#pragma unroll
    for (int m = 1; m < 64; m <<= 1) {
        a0 += __shfl_xor(a0, m, 64);
        a1v += __shfl_xor(a1v, m, 64);
        ws += __shfl_xor(ws, m, 64);
    }
    if (lane == 0) {
        float inv = 1.f / (ws + 1e-16f);
        float o0 = a0 * inv + b2[0];
        float o1 = a1v * inv + b2[1];
        float mx = fmaxf(o0, o1);
        float lse = mx + __logf(__expf(o0 - mx) + __expf(o1 - mx));
        out[2 * n] = o0 - lse;
        out[2 * n + 1] = o1 - lse;
    }
}

extern "C" void kernel_launch(void* const* d_in, const int* in_sizes, int n_in,
                              void* d_out, int out_size, void* d_ws, size_t ws_size,
                              hipStream_t stream) {
    const float* x   = (const float*)d_in[0];
    const int*   ei  = (const int*)d_in[1];
    const float* W1  = (const float*)d_in[2];
    const float* as1 = (const float*)d_in[3];
    const float* ad1 = (const float*)d_in[4];
    const float* b1  = (const float*)d_in[5];
    const float* W2  = (const float*)d_in[6];
    const float* as2 = (const float*)d_in[7];
    const float* ad2 = (const float*)d_in[8];
    const float* b2  = (const float*)d_in[9];
    float* out = (float*)d_out;

    int N = out_size / 2;          // 100000
    int E = in_sizes[1] / 2;       // 3200000
    int K = (N + NPB - 1) / NPB;   // 500

    // workspace layout (4B units; pk first for 16B alignment)
    float* ws    = (float*)d_ws;
    float4* pk   = (float4*)ws;                      // N float4
    uint2* h1b   = (uint2*)(pk + (size_t)N);         // N*8 uint2 (bf16 h1)
    float* a1s   = (float*)(h1b + (size_t)N * 8);    // N*2
    float* a1d   = a1s + (size_t)N * 2;              // N*2
    int* deg     = (int*)(a1d + (size_t)N * 2);      // N
    int* off     = deg + N;                          // N
    int* srcs    = off + N;                          // K*CAP
    int* binned  = srcs + (size_t)K * CAP;           // K*CAP
    int* cursor  = binned + (size_t)K * CAP;         // K

    int nblkE = (E + CHUNK - 1) / CHUNK;             // 782

    hipMemsetAsync(cursor, 0, K * sizeof(int), stream);
    kbin<<<nblkE, 512, 0, stream>>>(ei, E, K, cursor, binned);
    k1<<<(N + 63) / 64, 256, 0, stream>>>(x, W1, as1, ad1, h1b, a1s, a1d, N);
    kfused<<<K, 512, 0, stream>>>(cursor, binned, h1b, a1s, a1d,
                                  b1, W2, as2, ad2, pk, srcs, off, deg, N);
    kagg2<<<(N + 3) / 4, 256, 0, stream>>>(off, deg, srcs, pk, b2, out, N);
}

// Round 7
// 245.792 us; speedup vs baseline: 1.2140x; 1.2140x over previous
//
#include <hip/hip_runtime.h>
#include <hip/hip_bf16.h>

#define LEAK  0.2f
#define NPB   200       // nodes per dst-bucket -> K = ceil(N/NPB) = 500
#define CAP   8192      // padded per-bucket capacity (mean 6400, sigma 80)
#define CAPSH 13        // log2(CAP)
#define SBITS 17        // bits for src id (N=100000 < 2^17)
#define SMASK 0x1FFFF
#define CHUNK 4096      // edges per kbin block (8 per thread at 512 thr)

// ---------------------------------------------------------------------------
// kbin: probe edge_index layout (int64 vs int32), LDS histogram of
// dst-buckets, in-place scan, reserve per-bucket runs (1 global atomic per
// block,bucket), stage int2 in LDS, write packed (s | dloc<<17) records into
// padded per-bucket slices of `binned`.
// ---------------------------------------------------------------------------
__global__ __launch_bounds__(512) void kbin(const int* __restrict__ ei, int E, int K,
                                            int* __restrict__ cursor,
                                            int* __restrict__ binned) {
    __shared__ int hist[512], lo[512], gb[512], lc[512];
    __shared__ int2 stag[CHUNK];
    __shared__ int probe;
    int t = threadIdx.x;
    hist[t] = 0;
    if (t == 0) probe = 0;
    __syncthreads();
    if (t < 256) {
        int zc = 0;
#pragma unroll
        for (int j = 0; j < 4; j++) zc += (ei[(t * 4 + j) * 2 + 1] == 0) ? 1 : 0;
        if (zc) atomicAdd(&probe, zc);
    }
    __syncthreads();
    int f = (probe == 1024);
    int e0 = blockIdx.x * CHUNK;
    int ss[8], dd[8];
#pragma unroll
    for (int i = 0; i < 8; i++) {
        int e = e0 + t + 512 * i;
        ss[i] = -1;
        dd[i] = 0;
        if (e < E) {
            int s, d;
            if (f) { s = ei[2 * (long long)e]; d = ei[2 * ((long long)e + E)]; }
            else   { s = ei[e];                d = ei[(long long)e + E]; }
            ss[i] = s;
            dd[i] = d;
            atomicAdd(&hist[d / NPB], 1);
        }
    }
    __syncthreads();
    int v = hist[t], x = v;
    for (int o = 1; o < 512; o <<= 1) {
        int y = (t >= o) ? hist[t - o] : 0;
        __syncthreads();
        x += y;
        hist[t] = x;
        __syncthreads();
    }
    int tb = x - v;
    lo[t] = tb;
    lc[t] = tb;
    if (t < K && v) {
        int rel = atomicAdd(&cursor[t], v);
        gb[t] = (t << CAPSH) + rel;
    }
    __syncthreads();
#pragma unroll
    for (int i = 0; i < 8; i++) {
        if (ss[i] >= 0) {
            int bk = dd[i] / NPB;
            int pos = atomicAdd(&lc[bk], 1);
            stag[pos] = make_int2(ss[i], dd[i]);
        }
    }
    __syncthreads();
    int cnt = min(CHUNK, E - e0);
#pragma unroll
    for (int i = 0; i < 8; i++) {
        int idx = t + 512 * i;
        if (idx < cnt) {
            int2 sd2 = stag[idx];
            int bk = sd2.y / NPB;
            int dloc = sd2.y - bk * NPB;
            int gpos = gb[bk] + (idx - lo[bk]);
            if (gpos < ((bk + 1) << CAPSH))           // OOB safety clamp
                binned[gpos] = sd2.x | (dloc << SBITS);
        }
    }
}

// ---------------------------------------------------------------------------
// k1: h1[N,32] = x[N,128] @ W1[128,32]; a1s/a1d[N,2] attention scalars.
// ---------------------------------------------------------------------------
__global__ __launch_bounds__(256) void k1(const float* __restrict__ x,
                                          const float* __restrict__ W1,
                                          const float* __restrict__ atts,
                                          const float* __restrict__ attd,
                                          float* __restrict__ h1,
                                          float* __restrict__ a1s,
                                          float* __restrict__ a1d, int N) {
    __shared__ float Ws[128 * 32];
    __shared__ float xs[64 * 132];
    int t = threadIdx.x;
    const float4* W4 = (const float4*)W1;
    float4* Ws4 = (float4*)Ws;
#pragma unroll
    for (int i = 0; i < 4; i++) Ws4[t + 256 * i] = W4[t + 256 * i];
    long long node0 = (long long)blockIdx.x * 64;
    const float4* x4 = (const float4*)x;
    float4* xs4 = (float4*)xs;
#pragma unroll
    for (int i = 0; i < 8; i++) {
        int idx = t + 256 * i;
        int row = idx >> 5, col = idx & 31;
        long long n = node0 + row;
        float4 v = make_float4(0.f, 0.f, 0.f, 0.f);
        if (n < N) v = x4[n * 32 + col];
        xs4[row * 33 + col] = v;
    }
    __syncthreads();

    int cg = t & 7, ns = t >> 3;
    const float4* xr0 = (const float4*)(xs + (ns * 2) * 132);
    const float4* xr1 = (const float4*)(xs + (ns * 2 + 1) * 132);
    float acc0[4] = {0.f, 0.f, 0.f, 0.f}, acc1[4] = {0.f, 0.f, 0.f, 0.f};
#pragma unroll 8
    for (int k4 = 0; k4 < 32; k4++) {
        float4 xa = xr0[k4], xb = xr1[k4];
        float av[4] = {xa.x, xa.y, xa.z, xa.w};
        float bv[4] = {xb.x, xb.y, xb.z, xb.w};
#pragma unroll
        for (int i = 0; i < 4; i++) {
            float4 w = Ws4[(k4 * 4 + i) * 8 + cg];
            acc0[0] = fmaf(av[i], w.x, acc0[0]);
            acc0[1] = fmaf(av[i], w.y, acc0[1]);
            acc0[2] = fmaf(av[i], w.z, acc0[2]);
            acc0[3] = fmaf(av[i], w.w, acc0[3]);
            acc1[0] = fmaf(bv[i], w.x, acc1[0]);
            acc1[1] = fmaf(bv[i], w.y, acc1[1]);
            acc1[2] = fmaf(bv[i], w.z, acc1[2]);
            acc1[3] = fmaf(bv[i], w.w, acc1[3]);
        }
    }
    long long gn0 = node0 + ns * 2, gn1 = gn0 + 1;
    float4* h14 = (float4*)h1;
    if (gn0 < N) h14[gn0 * 8 + cg] = make_float4(acc0[0], acc0[1], acc0[2], acc0[3]);
    if (gn1 < N) h14[gn1 * 8 + cg] = make_float4(acc1[0], acc1[1], acc1[2], acc1[3]);

    float ps0 = 0.f, pd0 = 0.f, ps1 = 0.f, pd1 = 0.f;
#pragma unroll
    for (int i = 0; i < 4; i++) {
        float aa = atts[cg * 4 + i], dd = attd[cg * 4 + i];
        ps0 = fmaf(acc0[i], aa, ps0);
        pd0 = fmaf(acc0[i], dd, pd0);
        ps1 = fmaf(acc1[i], aa, ps1);
        pd1 = fmaf(acc1[i], dd, pd1);
    }
#pragma unroll
    for (int m = 1; m < 4; m <<= 1) {
        ps0 += __shfl_xor(ps0, m, 64);
        pd0 += __shfl_xor(pd0, m, 64);
        ps1 += __shfl_xor(ps1, m, 64);
        pd1 += __shfl_xor(pd1, m, 64);
    }
    if ((cg & 3) == 0) {
        int hd = cg >> 2;
        if (gn0 < N) { a1s[gn0 * 2 + hd] = ps0; a1d[gn0 * 2 + hd] = pd0; }
        if (gn1 < N) { a1s[gn1 * 2 + hd] = ps1; a1d[gn1 * 2 + hd] = pd1; }
    }
}

// ---------------------------------------------------------------------------
// kfused: one block per bucket, 1024 threads (16 waves) for near-100% wave
// occupancy at K=500 blocks (500*16 = 8000 of 8192 wave slots).
// Phase 1: bucket CSR in LDS (deg-hist, scan, scatter) + write srcs/off/deg
//          to global for kagg2.
// Phase 2: 16 waves aggregate the bucket's 200 nodes (layer-1 softmax-
//          gather, 8 edges x 8 channel-quads per iter, float4 h1 loads),
//          fused with normalize + bias + ELU + W2 proj + layer-2 attn
//          scalars -> pk.
// ---------------------------------------------------------------------------
__global__ __launch_bounds__(1024) void kfused(const int* __restrict__ cursor,
                                               const int* __restrict__ binned,
                                               const float* __restrict__ h1,
                                               const float* __restrict__ a1s,
                                               const float* __restrict__ a1d,
                                               const float* __restrict__ b1,
                                               const float* __restrict__ W2,
                                               const float* __restrict__ as2,
                                               const float* __restrict__ ad2,
                                               float4* __restrict__ pk,
                                               int* __restrict__ srcs,
                                               int* __restrict__ off,
                                               int* __restrict__ deg, int N) {
    __shared__ int lsrc[CAP];                 // 32 KB
    __shared__ int ldeg[NPB], lcur[NPB], loff[NPB];
    __shared__ int sd[1024];
    int b = blockIdx.x, t = threadIdx.x;
    int node0 = b * NPB;
    int nn = min(NPB, N - node0);
    int cnt = cursor[b];
    if (cnt > CAP) cnt = CAP;
    const int* bb = binned + ((long long)b << CAPSH);
    if (t < NPB) ldeg[t] = 0;
    __syncthreads();
    for (int i = t; i < cnt; i += 1024) atomicAdd(&ldeg[bb[i] >> SBITS], 1);
    __syncthreads();
    int v = (t < nn) ? ldeg[t] : 0, x = v;
    sd[t] = x;
    __syncthreads();
    for (int o = 1; o < 1024; o <<= 1) {
        int y = (t >= o) ? sd[t - o] : 0;
        __syncthreads();
        x += y;
        sd[t] = x;
        __syncthreads();
    }
    if (t < nn) {
        int rel = x - v;
        loff[t] = rel;
        lcur[t] = rel;
        off[node0 + t] = (b << CAPSH) + rel;
        deg[node0 + t] = v;
    }
    __syncthreads();
    for (int i = t; i < cnt; i += 1024) {
        int p = bb[i];
        int pos = atomicAdd(&lcur[p >> SBITS], 1);
        lsrc[pos] = p & SMASK;
    }
    __syncthreads();
    // srcs for kagg2 (coalesced stream write)
    for (int i = t; i < cnt; i += 1024) srcs[((long long)b << CAPSH) + i] = lsrc[i];

    // ---- phase 2 ----
    int wv = t >> 6, lane = t & 63;
    int e8 = lane >> 3, c4 = lane & 7, hd = c4 >> 2;
    bool wlane = (c4 & 3) == 0;
    const float4* h14 = (const float4*)h1;
    for (int ni = wv; ni < nn; ni += 16) {
        int n = node0 + ni;
        float a1dn = a1d[2 * n + hd];
        int base = loff[ni], g = ldeg[ni];
        float4 acc = make_float4(0.f, 0.f, 0.f, 0.f);
        float wsum = 0.f;
        // tt = -1 is the self-loop (edge slot 0)
        for (int tt = e8 - 1; tt < g; tt += 8) {
            int s = (tt < 0) ? n : lsrc[base + tt];
            float al = a1s[2 * s + hd] + a1dn;
            al = al > 0.f ? al : LEAK * al;
            float w = __expf(al);
            float4 hv = h14[(size_t)s * 8 + c4];
            acc.x = fmaf(w, hv.x, acc.x);
            acc.y = fmaf(w, hv.y, acc.y);
            acc.z = fmaf(w, hv.z, acc.z);
            acc.w = fmaf(w, hv.w, acc.w);
            if (wlane) wsum += w;
        }
#pragma unroll
        for (int m = 8; m < 64; m <<= 1) {
            acc.x += __shfl_xor(acc.x, m, 64);
            acc.y += __shfl_xor(acc.y, m, 64);
            acc.z += __shfl_xor(acc.z, m, 64);
            acc.w += __shfl_xor(acc.w, m, 64);
            wsum += __shfl_xor(wsum, m, 64);
        }
        float wsH = __shfl(wsum, hd * 4, 64);
        float inv = 1.f / (wsH + 1e-16f);
        float4 bv = ((const float4*)b1)[c4];
        float4 t1;
        t1.x = acc.x * inv + bv.x;
        t1.y = acc.y * inv + bv.y;
        t1.z = acc.z * inv + bv.z;
        t1.w = acc.w * inv + bv.w;
        t1.x = t1.x > 0.f ? t1.x : __expf(t1.x) - 1.f;
        t1.y = t1.y > 0.f ? t1.y : __expf(t1.y) - 1.f;
        t1.z = t1.z > 0.f ? t1.z : __expf(t1.z) - 1.f;
        t1.w = t1.w > 0.f ? t1.w : __expf(t1.w) - 1.f;
        const float4* W24 = (const float4*)W2;
        float4 wA = W24[c4 * 2], wB = W24[c4 * 2 + 1];
        float p0 = t1.x * wA.x + t1.y * wA.z + t1.z * wB.x + t1.w * wB.z;
        float p1 = t1.x * wA.y + t1.y * wA.w + t1.z * wB.y + t1.w * wB.w;
#pragma unroll
        for (int m = 1; m < 8; m <<= 1) {
            p0 += __shfl_xor(p0, m, 64);
            p1 += __shfl_xor(p1, m, 64);
        }
        if (lane == 0)
            pk[n] = make_float4(p0 * as2[0] + p1 * as2[1], p0, p1,
                                p0 * ad2[0] + p1 * ad2[1]);
    }
}

// ---------------------------------------------------------------------------
// kagg2: layer-2 gather, one wave per node, 1 packed 16B load per edge,
// + log_softmax -> out
// ---------------------------------------------------------------------------
__global__ __launch_bounds__(256) void kagg2(const int* __restrict__ off,
                                             const int* __restrict__ deg,
                                             const int* __restrict__ srcs,
                                             const float4* __restrict__ pk,
                                             const float* __restrict__ b2,
                                             float* __restrict__ out, int N) {
    int wv = threadIdx.x >> 6;
    int lane = threadIdx.x & 63;
    int n = blockIdx.x * 4 + wv;
    if (n >= N) return;
    float adn = pk[n].w;
    int base = off[n], g = deg[n];
    float a0 = 0.f, a1v = 0.f, ws = 0.f;
    for (int t = lane - 1; t < g; t += 64) {
        int s = (t < 0) ? n : srcs[base + t];
        float4 p = pk[s];
        float al = p.x + adn;
        al = al > 0.f ? al : LEAK * al;
        float w = __expf(al);
        a0 = fmaf(w, p.y, a0);
        a1v = fmaf(w, p.z, a1v);
        ws += w;
    }
#pragma unroll
    for (int m = 1; m < 64; m <<= 1) {
        a0 += __shfl_xor(a0, m, 64);
        a1v += __shfl_xor(a1v, m, 64);
        ws += __shfl_xor(ws, m, 64);
    }
    if (lane == 0) {
        float inv = 1.f / (ws + 1e-16f);
        float o0 = a0 * inv + b2[0];
        float o1 = a1v * inv + b2[1];
        float mx = fmaxf(o0, o1);
        float lse = mx + __logf(__expf(o0 - mx) + __expf(o1 - mx));
        out[2 * n] = o0 - lse;
        out[2 * n + 1] = o1 - lse;
    }
}

extern "C" void kernel_launch(void* const* d_in, const int* in_sizes, int n_in,
                              void* d_out, int out_size, void* d_ws, size_t ws_size,
                              hipStream_t stream) {
    const float* x   = (const float*)d_in[0];
    const int*   ei  = (const int*)d_in[1];
    const float* W1  = (const float*)d_in[2];
    const float* as1 = (const float*)d_in[3];
    const float* ad1 = (const float*)d_in[4];
    const float* b1  = (const float*)d_in[5];
    const float* W2  = (const float*)d_in[6];
    const float* as2 = (const float*)d_in[7];
    const float* ad2 = (const float*)d_in[8];
    const float* b2  = (const float*)d_in[9];
    float* out = (float*)d_out;

    int N = out_size / 2;          // 100000
    int E = in_sizes[1] / 2;       // 3200000
    int K = (N + NPB - 1) / NPB;   // 500

    // workspace layout (4B units; h1 first keeps pk 16B-aligned)
    float* ws    = (float*)d_ws;
    float* h1    = ws;                               // N*32
    float4* pk   = (float4*)(h1 + (size_t)N * 32);   // N float4
    float* a1s   = (float*)(pk + (size_t)N);         // N*2
    float* a1d   = a1s + (size_t)N * 2;              // N*2
    int* deg     = (int*)(a1d + (size_t)N * 2);      // N
    int* off     = deg + N;                          // N
    int* srcs    = off + N;                          // K*CAP
    int* binned  = srcs + (size_t)K * CAP;           // K*CAP
    int* cursor  = binned + (size_t)K * CAP;         // K

    int nblkE = (E + CHUNK - 1) / CHUNK;             // 782

    hipMemsetAsync(cursor, 0, K * sizeof(int), stream);
    kbin<<<nblkE, 512, 0, stream>>>(ei, E, K, cursor, binned);
    k1<<<(N + 63) / 64, 256, 0, stream>>>(x, W1, as1, ad1, h1, a1s, a1d, N);
    kfused<<<K, 1024, 0, stream>>>(cursor, binned, h1, a1s, a1d,
                                   b1, W2, as2, ad2, pk, srcs, off, deg, N);
    kagg2<<<(N + 3) / 4, 256, 0, stream>>>(off, deg, srcs, pk, b2, out, N);
}